// Round 1
// baseline (2998.526 us; speedup 1.0000x reference)
//
#include <hip/hip_runtime.h>
#include <cmath>

namespace {

enum : int { N = 128, T = 32, D = 512, H = 1024, V = 16384, R = N * T,
             BN_SC = 128, NVB = V / BN_SC };

// workspace layout in floats
enum : size_t {
  OFF_H0   = 0,                               // N*H
  OFF_HALL = OFF_H0 + (size_t)N * H,          // R*H
  OFF_XW   = OFF_HALL + (size_t)R * H,        // R*H
  OFF_PMAX = OFF_XW + (size_t)R * H,          // R*NVB
  OFF_PSUM = OFF_PMAX + (size_t)R * NVB,      // R*NVB
  OFF_TGT  = OFF_PSUM + (size_t)R * NVB,      // R
  OFF_BLK  = OFF_TGT + (size_t)R,             // 64
};

// ---------- h0 = features @ W_proj + b_proj ----------
__global__ __launch_bounds__(256) void k_h0(const float* __restrict__ feat,
                                            const float* __restrict__ Wp,
                                            const float* __restrict__ bp,
                                            float* __restrict__ h0) {
  int idx = blockIdx.x * 256 + threadIdx.x;   // n*H + h
  int n = idx >> 10, h = idx & (H - 1);
  const float* f = feat + (size_t)n * D;
  float acc = bp[h];
  for (int d = 0; d < D; d += 4) {
    float4 fv = *reinterpret_cast<const float4*>(f + d);
    acc += fv.x * Wp[(size_t)(d + 0) * H + h];
    acc += fv.y * Wp[(size_t)(d + 1) * H + h];
    acc += fv.z * Wp[(size_t)(d + 2) * H + h];
    acc += fv.w * Wp[(size_t)(d + 3) * H + h];
  }
  h0[idx] = acc;
}

// ---------- xW[r][h] = W_embed[cap_in[r]] @ Wx + b ----------
// 4 rows per thread to reuse Wx loads. grid = (R/4) * 4 h-chunks.
__global__ __launch_bounds__(256) void k_xw(const int* __restrict__ cap,
                                            const float* __restrict__ Wemb,
                                            const float* __restrict__ Wx,
                                            const float* __restrict__ b,
                                            float* __restrict__ xW) {
  int hb = blockIdx.x & 3;
  int r0 = (blockIdx.x >> 2) * 4;             // 4 consecutive rows, same n
  int h = hb * 256 + threadIdx.x;
  int n = r0 >> 5, t0 = r0 & 31;
  const float* xr0 = Wemb + (size_t)cap[n * 33 + t0 + 0] * D;
  const float* xr1 = Wemb + (size_t)cap[n * 33 + t0 + 1] * D;
  const float* xr2 = Wemb + (size_t)cap[n * 33 + t0 + 2] * D;
  const float* xr3 = Wemb + (size_t)cap[n * 33 + t0 + 3] * D;
  float bb = b[h];
  float a0 = bb, a1 = bb, a2 = bb, a3 = bb;
  for (int w = 0; w < D; ++w) {
    float wv = Wx[(size_t)w * H + h];
    a0 += xr0[w] * wv;
    a1 += xr1[w] * wv;
    a2 += xr2[w] * wv;
    a3 += xr3[w] * wv;
  }
  xW[(size_t)(r0 + 0) * H + h] = a0;
  xW[(size_t)(r0 + 1) * H + h] = a1;
  xW[(size_t)(r0 + 2) * H + h] = a2;
  xW[(size_t)(r0 + 3) * H + h] = a3;
}

// ---------- one RNN step: HALL[n*T+t] = tanh(xW[n*T+t] + hprev @ Wh) ----------
// 4 batch rows per thread. grid = 4 h-chunks * 32 n-groups = 128 blocks.
__global__ __launch_bounds__(256) void k_rnn(const float* __restrict__ hprev, int hp_stride,
                                             const float* __restrict__ Wh,
                                             const float* __restrict__ xW,
                                             float* __restrict__ HALL, int t) {
  int hb = blockIdx.x & 3;
  int n0 = (blockIdx.x >> 2) * 4;
  int h = hb * 256 + threadIdx.x;
  float a0 = xW[(size_t)((n0 + 0) * T + t) * H + h];
  float a1 = xW[(size_t)((n0 + 1) * T + t) * H + h];
  float a2 = xW[(size_t)((n0 + 2) * T + t) * H + h];
  float a3 = xW[(size_t)((n0 + 3) * T + t) * H + h];
  const float* hp0 = hprev + (size_t)(n0 + 0) * hp_stride;
  const float* hp1 = hprev + (size_t)(n0 + 1) * hp_stride;
  const float* hp2 = hprev + (size_t)(n0 + 2) * hp_stride;
  const float* hp3 = hprev + (size_t)(n0 + 3) * hp_stride;
  for (int k = 0; k < H; ++k) {
    float wv = Wh[(size_t)k * H + h];
    a0 += hp0[k] * wv;
    a1 += hp1[k] * wv;
    a2 += hp2[k] * wv;
    a3 += hp3[k] * wv;
  }
  HALL[(size_t)((n0 + 0) * T + t) * H + h] = tanhf(a0);
  HALL[(size_t)((n0 + 1) * T + t) * H + h] = tanhf(a1);
  HALL[(size_t)((n0 + 2) * T + t) * H + h] = tanhf(a2);
  HALL[(size_t)((n0 + 3) * T + t) * H + h] = tanhf(a3);
}

// ---------- scores tile GEMM + fused per-row online (max, sumexp) partials ----------
// block tile 128 rows x 128 cols, BK=16, 256 threads (16x16), 8x8 regs/thread.
__global__ __launch_bounds__(256) void k_scores(const float* __restrict__ A,   // HALL [R][H]
                                                const float* __restrict__ Wv,  // [H][V]
                                                const float* __restrict__ bv,
                                                const int* __restrict__ cap,
                                                float* __restrict__ pmax,
                                                float* __restrict__ psum,
                                                float* __restrict__ tgt) {
  const int BK = 16;
  __shared__ float As[BK][128 + 4];   // transposed: As[k][row]
  __shared__ float Bs[BK][128];
  int tid = threadIdx.x;
  int tx = tid & 15, ty = tid >> 4;
  int row0 = blockIdx.y * 128;
  int col0 = blockIdx.x * 128;

  float acc[8][8];
#pragma unroll
  for (int i = 0; i < 8; ++i)
#pragma unroll
    for (int j = 0; j < 8; ++j) acc[i][j] = 0.f;

  int r_l = tid >> 2;              // 0..63
  int j4 = (tid & 3) * 4;          // 0,4,8,12
  int kk = tid >> 4;               // 0..15
  int c8 = (tid & 15) * 8;

  for (int k0 = 0; k0 < H; k0 += BK) {
    float4 ga0 = *reinterpret_cast<const float4*>(&A[(size_t)(row0 + r_l) * H + k0 + j4]);
    float4 ga1 = *reinterpret_cast<const float4*>(&A[(size_t)(row0 + r_l + 64) * H + k0 + j4]);
    float4 gb0 = *reinterpret_cast<const float4*>(&Wv[(size_t)(k0 + kk) * V + col0 + c8]);
    float4 gb1 = *reinterpret_cast<const float4*>(&Wv[(size_t)(k0 + kk) * V + col0 + c8 + 4]);
    __syncthreads();   // previous iteration finished reading LDS
    As[j4 + 0][r_l] = ga0.x; As[j4 + 1][r_l] = ga0.y;
    As[j4 + 2][r_l] = ga0.z; As[j4 + 3][r_l] = ga0.w;
    As[j4 + 0][r_l + 64] = ga1.x; As[j4 + 1][r_l + 64] = ga1.y;
    As[j4 + 2][r_l + 64] = ga1.z; As[j4 + 3][r_l + 64] = ga1.w;
    *reinterpret_cast<float4*>(&Bs[kk][c8]) = gb0;
    *reinterpret_cast<float4*>(&Bs[kk][c8 + 4]) = gb1;
    __syncthreads();
#pragma unroll
    for (int k = 0; k < BK; ++k) {
      float4 av0 = *reinterpret_cast<const float4*>(&As[k][ty * 8]);
      float4 av1 = *reinterpret_cast<const float4*>(&As[k][ty * 8 + 4]);
      float4 bw0 = *reinterpret_cast<const float4*>(&Bs[k][tx * 8]);
      float4 bw1 = *reinterpret_cast<const float4*>(&Bs[k][tx * 8 + 4]);
      float av[8] = {av0.x, av0.y, av0.z, av0.w, av1.x, av1.y, av1.z, av1.w};
      float bw[8] = {bw0.x, bw0.y, bw0.z, bw0.w, bw1.x, bw1.y, bw1.z, bw1.w};
#pragma unroll
      for (int i = 0; i < 8; ++i)
#pragma unroll
        for (int j = 0; j < 8; ++j) acc[i][j] += av[i] * bw[j];
    }
  }

  // epilogue: + b_vocab, capture target score, per-row online (max, sumexp)
  float bb[8];
#pragma unroll
  for (int j = 0; j < 8; ++j) bb[j] = bv[col0 + tx * 8 + j];

  for (int i = 0; i < 8; ++i) {
    int r = row0 + ty * 8 + i;
    int n = r >> 5, t = r & 31;
    int tok = cap[n * 33 + t + 1];        // cap_out
    float m = -1e30f;
#pragma unroll
    for (int j = 0; j < 8; ++j) {
      float v = acc[i][j] + bb[j];
      acc[i][j] = v;
      if (col0 + tx * 8 + j == tok) tgt[r] = v;
      m = fmaxf(m, v);
    }
    for (int off = 8; off >= 1; off >>= 1) m = fmaxf(m, __shfl_xor(m, off, 16));
    float s = 0.f;
#pragma unroll
    for (int j = 0; j < 8; ++j) s += expf(acc[i][j] - m);
    for (int off = 8; off >= 1; off >>= 1) s += __shfl_xor(s, off, 16);
    if (tx == 0) {
      pmax[(size_t)r * NVB + blockIdx.x] = m;
      psum[(size_t)r * NVB + blockIdx.x] = s;
    }
  }
}

// ---------- combine partials -> per-row nll -> per-block sums ----------
__global__ __launch_bounds__(256) void k_loss(const float* __restrict__ pmax,
                                              const float* __restrict__ psum,
                                              const float* __restrict__ tgt,
                                              const int* __restrict__ cap,
                                              float* __restrict__ blk) {
  int r = blockIdx.x * 256 + threadIdx.x;   // 0..R-1
  float M = -1e30f;
  for (int b = 0; b < NVB; ++b) M = fmaxf(M, pmax[(size_t)r * NVB + b]);
  float S = 0.f;
  for (int b = 0; b < NVB; ++b) S += psum[(size_t)r * NVB + b] * expf(pmax[(size_t)r * NVB + b] - M);
  float lse = M + logf(S);
  int n = r >> 5, t = r & 31;
  int tok = cap[n * 33 + t + 1];
  float nll = (tok != 0) ? (lse - tgt[r]) : 0.f;

  __shared__ float red[256];
  red[threadIdx.x] = nll;
  __syncthreads();
  for (int s = 128; s > 0; s >>= 1) {
    if (threadIdx.x < s) red[threadIdx.x] += red[threadIdx.x + s];
    __syncthreads();
  }
  if (threadIdx.x == 0) blk[blockIdx.x] = red[0];
}

__global__ void k_final(const float* __restrict__ blk, float* __restrict__ out) {
  if (threadIdx.x == 0) {
    float s = 0.f;
    for (int i = 0; i < R / 256; ++i) s += blk[i];
    out[0] = s * (1.0f / 128.0f);
  }
}

}  // namespace

extern "C" void kernel_launch(void* const* d_in, const int* in_sizes, int n_in,
                              void* d_out, int out_size, void* d_ws, size_t ws_size,
                              hipStream_t stream) {
  const float* feat = (const float*)d_in[0];
  const int*   cap  = (const int*)d_in[1];
  const float* Wp   = (const float*)d_in[2];
  const float* bp   = (const float*)d_in[3];
  const float* Wemb = (const float*)d_in[4];
  const float* Wx   = (const float*)d_in[5];
  const float* Wh   = (const float*)d_in[6];
  const float* b    = (const float*)d_in[7];
  const float* Wv   = (const float*)d_in[8];
  const float* bv   = (const float*)d_in[9];

  float* ws   = (float*)d_ws;
  float* h0   = ws + OFF_H0;
  float* HALL = ws + OFF_HALL;
  float* xW   = ws + OFF_XW;
  float* pmax = ws + OFF_PMAX;
  float* psum = ws + OFF_PSUM;
  float* tgtb = ws + OFF_TGT;
  float* blk  = ws + OFF_BLK;

  hipLaunchKernelGGL(k_h0, dim3(N * H / 256), dim3(256), 0, stream, feat, Wp, bp, h0);
  hipLaunchKernelGGL(k_xw, dim3(R), dim3(256), 0, stream, cap, Wemb, Wx, b, xW);
  for (int t = 0; t < T; ++t) {
    const float* hp = (t == 0) ? h0 : (HALL + (size_t)(t - 1) * H);
    int stride = (t == 0) ? H : T * H;
    hipLaunchKernelGGL(k_rnn, dim3(128), dim3(256), 0, stream, hp, stride, Wh, xW, HALL, t);
  }
  hipLaunchKernelGGL(k_scores, dim3(NVB, R / 128), dim3(256), 0, stream,
                     HALL, Wv, bv, cap, pmax, psum, tgtb);
  hipLaunchKernelGGL(k_loss, dim3(R / 256), dim3(256), 0, stream, pmax, psum, tgtb, cap, blk);
  hipLaunchKernelGGL(k_final, dim3(1), dim3(64), 0, stream, blk, (float*)d_out);
}

// Round 3
// 822.311 us; speedup vs baseline: 3.6465x; 3.6465x over previous
//
#include <hip/hip_runtime.h>
#include <cmath>

namespace {

typedef __bf16 bf16x8 __attribute__((ext_vector_type(8)));
typedef float f32x4 __attribute__((ext_vector_type(4)));

enum : int { N = 128, T = 32, D = 512, H = 1024, V = 16384, R = N * T, NP = V / 64 };

// ---- workspace layout (float units) ----
enum : size_t {
  OFF_XB    = 0,                                // 4096x512 bf16   -> 1,048,576 fl
  OFF_FEATB = OFF_XB + 1048576,                 // 128x512 bf16    -> 32,768
  OFF_H0B   = OFF_FEATB + 32768,                // 128x1024 bf16   -> 65,536
  OFF_HALLB = OFF_H0B + 65536,                  // 4096x1024 bf16  -> 2,097,152
  OFF_WPT   = OFF_HALLB + 2097152,              // 1024x512 bf16   -> 262,144
  OFF_WXT   = OFF_WPT + 262144,                 // 1024x512 bf16   -> 262,144
  OFF_WHT   = OFF_WXT + 262144,                 // 1024x1024 bf16  -> 524,288
  OFF_WVT   = OFF_WHT + 524288,                 // 16384x1024 bf16 -> 8,388,608
  OFF_XW    = OFF_WVT + 8388608,                // 4096x1024 f32   -> 4,194,304
  OFF_PMAX  = OFF_XW + 4194304,                 // 4096x256 f32
  OFF_PSUM  = OFF_PMAX + 1048576,
  OFF_BLK   = OFF_PSUM + 1048576,               // 1024
};

__device__ inline unsigned short f2b(float x) {
  union { float f; unsigned u; } v; v.f = x;
  unsigned r = v.u + 0x7fffu + ((v.u >> 16) & 1u);
  return (unsigned short)(r >> 16);
}
__device__ inline float b2f(unsigned short b) {
  union { unsigned u; float f; } v; v.u = ((unsigned)b) << 16; return v.f;
}

#define GLOAD_LDS16(gptr, lptr)                                            \
  __builtin_amdgcn_global_load_lds(                                        \
      (const __attribute__((address_space(1))) unsigned int*)(gptr),       \
      (__attribute__((address_space(3))) unsigned int*)(lptr), 16, 0, 0)

// ---------- convert + transpose: dst[n][k] = bf16(src[k][n]) ----------
__global__ __launch_bounds__(256) void k_cvt_t(const float* __restrict__ src,
                                               unsigned short* __restrict__ dst,
                                               int Ks, int Ns) {
  __shared__ float tile[32][33];
  int tx = threadIdx.x & 31, ty = threadIdx.x >> 5;
  int n0 = blockIdx.x * 32, k0 = blockIdx.y * 32;
#pragma unroll
  for (int i = 0; i < 4; ++i)
    tile[ty + i * 8][tx] = src[(size_t)(k0 + ty + i * 8) * Ns + n0 + tx];
  __syncthreads();
#pragma unroll
  for (int i = 0; i < 4; ++i)
    dst[(size_t)(n0 + ty + i * 8) * Ks + k0 + tx] = f2b(tile[tx][ty + i * 8]);
}

// ---------- elementwise fp32 -> bf16 (2 elems/thread) ----------
__global__ __launch_bounds__(256) void k_cvt(const float* __restrict__ src,
                                             unsigned short* __restrict__ dst) {
  int i = (blockIdx.x * 256 + threadIdx.x) * 2;
  float2 v = *reinterpret_cast<const float2*>(src + i);
  ushort2 o; o.x = f2b(v.x); o.y = f2b(v.y);
  *reinterpret_cast<ushort2*>(dst + i) = o;
}

// ---------- gather embeddings + cvt: XB[r][w] = bf16(Wemb[cap_in[r]][w]) ----------
__global__ __launch_bounds__(256) void k_gather(const int* __restrict__ cap,
                                                const float* __restrict__ Wemb,
                                                unsigned short* __restrict__ XB) {
  int idx = blockIdx.x * 256 + threadIdx.x;  // one thread = 2 elems
  int r = idx >> 8;
  int w2 = (idx & 255) * 2;
  int n = r >> 5, t = r & 31;
  const float* srow = Wemb + (size_t)cap[n * 33 + t] * D;
  float2 v = *reinterpret_cast<const float2*>(srow + w2);
  ushort2 o; o.x = f2b(v.x); o.y = f2b(v.y);
  *reinterpret_cast<ushort2*>(XB + (size_t)r * D + w2) = o;
}

// ---------- bf16 MFMA GEMM: C[M][N] = A[M][K] * B^T where B is [N][K] ----------
// EPI: 0 = f32 store + bias; 1 = bf16 store + bias; 2 = bf16 tanh(acc+addend);
//      3 = fused per-row (max, sumexp) partials at 64-col granularity
template <int BM, int BN, int WM, int WN, int EPI>
__global__ __launch_bounds__(256) void gemm_bt(
    const unsigned short* __restrict__ A, int lda,
    const unsigned short* __restrict__ B, int K,
    void* __restrict__ C, int ldc,
    const float* __restrict__ bias,
    const float* __restrict__ addend,
    float* __restrict__ pmax, float* __restrict__ psum) {
  constexpr int BK = 64;
  constexpr int WAVES_N = BN / WN;
  constexpr int NW = (BM / WM) * (BN / WN);
  constexpr int FM = WM / 16, FN = WN / 16;
  __shared__ __align__(16) unsigned short As[BM * BK];
  __shared__ __align__(16) unsigned short Bs[BN * BK];
  int tid = threadIdx.x, lane = tid & 63, wave = tid >> 6;
  int wr = wave / WAVES_N, wc = wave % WAVES_N;
  int row0 = blockIdx.y * BM, col0 = blockIdx.x * BN;

  f32x4 acc[FM][FN] = {};
  const unsigned short* Ab = A + (size_t)row0 * lda;
  const unsigned short* Bb = B + (size_t)col0 * K;
  int srow = lane >> 3, skof = (lane & 7) * 8;

  for (int k0 = 0; k0 < K; k0 += BK) {
    __syncthreads();  // all waves done reading LDS from previous iter
#pragma unroll
    for (int c = wave; c < BM / 8; c += NW) {
      const unsigned short* g = Ab + (size_t)(c * 8 + srow) * lda + k0 + skof;
      GLOAD_LDS16(g, As + c * 512);
    }
#pragma unroll
    for (int c = wave; c < BN / 8; c += NW) {
      const unsigned short* g = Bb + (size_t)(c * 8 + srow) * K + k0 + skof;
      GLOAD_LDS16(g, Bs + c * 512);
    }
    asm volatile("s_waitcnt vmcnt(0)" ::: "memory");
    __syncthreads();
#pragma unroll
    for (int kk = 0; kk < 2; ++kk) {
      bf16x8 af[FM], bfr[FN];
#pragma unroll
      for (int m = 0; m < FM; ++m)
        af[m] = *reinterpret_cast<const bf16x8*>(
            &As[(wr * WM + m * 16 + (lane & 15)) * BK + kk * 32 + (lane >> 4) * 8]);
#pragma unroll
      for (int n = 0; n < FN; ++n)
        bfr[n] = *reinterpret_cast<const bf16x8*>(
            &Bs[(wc * WN + n * 16 + (lane & 15)) * BK + kk * 32 + (lane >> 4) * 8]);
#pragma unroll
      for (int m = 0; m < FM; ++m)
#pragma unroll
        for (int n = 0; n < FN; ++n)
          acc[m][n] = __builtin_amdgcn_mfma_f32_16x16x32_bf16(af[m], bfr[n], acc[m][n], 0, 0, 0);
    }
  }

  int lr4 = (lane >> 4) * 4, lc = lane & 15;
  if constexpr (EPI == 3) {
    float bb[FN];
#pragma unroll
    for (int n = 0; n < FN; ++n) bb[n] = bias[col0 + wc * WN + n * 16 + lc];
    int p = (col0 + wc * WN) >> 6;  // WN == 64
#pragma unroll
    for (int m = 0; m < FM; ++m) {
#pragma unroll
      for (int j = 0; j < 4; ++j) {
        int r = row0 + wr * WM + m * 16 + lr4 + j;
        float vs[FN], vmax = -1e30f;
#pragma unroll
        for (int n = 0; n < FN; ++n) {
          vs[n] = acc[m][n][j] + bb[n];
          vmax = fmaxf(vmax, vs[n]);
        }
#pragma unroll
        for (int off = 8; off >= 1; off >>= 1) vmax = fmaxf(vmax, __shfl_xor(vmax, off));
        float se = 0.f;
#pragma unroll
        for (int n = 0; n < FN; ++n) se += expf(vs[n] - vmax);
#pragma unroll
        for (int off = 8; off >= 1; off >>= 1) se += __shfl_xor(se, off);
        if (lc == 0) {
          pmax[(size_t)r * NP + p] = vmax;
          psum[(size_t)r * NP + p] = se;
        }
      }
    }
  } else {
#pragma unroll
    for (int m = 0; m < FM; ++m)
#pragma unroll
      for (int n = 0; n < FN; ++n) {
        int cg = col0 + wc * WN + n * 16 + lc;
        float bcol = (EPI == 2) ? 0.f : bias[cg];
#pragma unroll
        for (int j = 0; j < 4; ++j) {
          int r = row0 + wr * WM + m * 16 + lr4 + j;
          float v = acc[m][n][j] + bcol;
          if constexpr (EPI == 0) {
            ((float*)C)[(size_t)r * ldc + cg] = v;
          } else if constexpr (EPI == 1) {
            ((unsigned short*)C)[(size_t)r * ldc + cg] = f2b(v);
          } else {  // EPI == 2
            v = tanhf(v + addend[(size_t)r * ldc + cg]);
            ((unsigned short*)C)[(size_t)r * ldc + cg] = f2b(v);
          }
        }
      }
  }
}

// ---------- combine partials + target dot -> per-block nll sums ----------
__global__ __launch_bounds__(256) void k_loss(const float* __restrict__ pmax,
                                              const float* __restrict__ psum,
                                              const unsigned short* __restrict__ HALLB,
                                              const unsigned short* __restrict__ WvT,
                                              const float* __restrict__ bv,
                                              const int* __restrict__ cap,
                                              float* __restrict__ blk) {
  int wave = threadIdx.x >> 6, lane = threadIdx.x & 63;
  int r = blockIdx.x * 4 + wave;
  float M = -1e30f;
  for (int i = lane; i < NP; i += 64) M = fmaxf(M, pmax[(size_t)r * NP + i]);
#pragma unroll
  for (int off = 32; off >= 1; off >>= 1) M = fmaxf(M, __shfl_xor(M, off));
  float S = 0.f;
  for (int i = lane; i < NP; i += 64) S += psum[(size_t)r * NP + i] * expf(pmax[(size_t)r * NP + i] - M);
#pragma unroll
  for (int off = 32; off >= 1; off >>= 1) S += __shfl_xor(S, off);
  float lse = M + logf(S);
  int n = r >> 5, t = r & 31;
  int tok = cap[n * 33 + t + 1];
  const unsigned short* hr = HALLB + (size_t)r * H + lane * 16;
  const unsigned short* wr_ = WvT + (size_t)tok * H + lane * 16;
  float d = 0.f;
#pragma unroll
  for (int i = 0; i < 16; ++i) d += b2f(hr[i]) * b2f(wr_[i]);
#pragma unroll
  for (int off = 32; off >= 1; off >>= 1) d += __shfl_xor(d, off);
  float nll = (tok != 0) ? (lse - (d + bv[tok])) : 0.f;
  __shared__ float red[4];
  if (lane == 0) red[wave] = nll;
  __syncthreads();
  if (threadIdx.x == 0) blk[blockIdx.x] = red[0] + red[1] + red[2] + red[3];
}

__global__ __launch_bounds__(256) void k_final(const float* __restrict__ blk,
                                               float* __restrict__ out) {
  __shared__ float red[256];
  float s = 0.f;
  for (int i = threadIdx.x; i < R / 4; i += 256) s += blk[i];
  red[threadIdx.x] = s;
  __syncthreads();
  for (int st = 128; st >= 1; st >>= 1) {
    if (threadIdx.x < st) red[threadIdx.x] += red[threadIdx.x + st];
    __syncthreads();
  }
  if (threadIdx.x == 0) out[0] = red[0] * (1.0f / 128.0f);
}

}  // namespace

extern "C" void kernel_launch(void* const* d_in, const int* in_sizes, int n_in,
                              void* d_out, int out_size, void* d_ws, size_t ws_size,
                              hipStream_t stream) {
  const float* feat = (const float*)d_in[0];
  const int*   cap  = (const int*)d_in[1];
  const float* Wp   = (const float*)d_in[2];
  const float* bp   = (const float*)d_in[3];
  const float* Wemb = (const float*)d_in[4];
  const float* Wx   = (const float*)d_in[5];
  const float* Wh   = (const float*)d_in[6];
  const float* b    = (const float*)d_in[7];
  const float* Wv   = (const float*)d_in[8];
  const float* bv   = (const float*)d_in[9];

  float* ws = (float*)d_ws;
  unsigned short* XB    = (unsigned short*)(ws + OFF_XB);
  unsigned short* featB = (unsigned short*)(ws + OFF_FEATB);
  unsigned short* h0B   = (unsigned short*)(ws + OFF_H0B);
  unsigned short* HALLB = (unsigned short*)(ws + OFF_HALLB);
  unsigned short* WpT   = (unsigned short*)(ws + OFF_WPT);
  unsigned short* WxT   = (unsigned short*)(ws + OFF_WXT);
  unsigned short* WhT   = (unsigned short*)(ws + OFF_WHT);
  unsigned short* WvT   = (unsigned short*)(ws + OFF_WVT);
  float* xW   = ws + OFF_XW;
  float* pmax = ws + OFF_PMAX;
  float* psum = ws + OFF_PSUM;
  float* blk  = ws + OFF_BLK;

  // weight converts/transposes (bf16, B^T layout)
  hipLaunchKernelGGL(k_cvt_t, dim3(H / 32, D / 32), dim3(256), 0, stream, Wp, WpT, D, H);
  hipLaunchKernelGGL(k_cvt_t, dim3(H / 32, D / 32), dim3(256), 0, stream, Wx, WxT, D, H);
  hipLaunchKernelGGL(k_cvt_t, dim3(H / 32, H / 32), dim3(256), 0, stream, Wh, WhT, H, H);
  hipLaunchKernelGGL(k_cvt_t, dim3(V / 32, H / 32), dim3(256), 0, stream, Wv, WvT, H, V);
  hipLaunchKernelGGL(k_cvt, dim3(N * D / 512), dim3(256), 0, stream, feat, featB);
  hipLaunchKernelGGL(k_gather, dim3(R * D / 512), dim3(256), 0, stream, cap, Wemb, XB);

  // h0 = featB @ Wp^T + bp   (bf16 out)
  hipLaunchKernelGGL((gemm_bt<128, 128, 64, 64, 1>), dim3(H / 128, 1), dim3(256), 0, stream,
                     featB, D, WpT, D, (void*)h0B, H, bp, nullptr, nullptr, nullptr);
  // xW = XB @ Wx^T + b   (f32 out)
  hipLaunchKernelGGL((gemm_bt<128, 128, 64, 64, 0>), dim3(H / 128, R / 128), dim3(256), 0, stream,
                     XB, D, WxT, D, (void*)xW, H, b, nullptr, nullptr, nullptr);
  // recurrence: HALLB[n*T+t] = tanh(xW[n*T+t] + hprev @ Wh^T)
  for (int t = 0; t < T; ++t) {
    const unsigned short* Aptr = (t == 0) ? h0B : (HALLB + (size_t)(t - 1) * H);
    int lda = (t == 0) ? H : T * H;
    hipLaunchKernelGGL((gemm_bt<64, 64, 32, 32, 2>), dim3(H / 64, N / 64), dim3(256), 0, stream,
                       Aptr, lda, WhT, H, (void*)(HALLB + (size_t)t * H), T * H,
                       nullptr, xW + (size_t)t * H, nullptr, nullptr);
  }
  // scores partials
  hipLaunchKernelGGL((gemm_bt<128, 128, 64, 64, 3>), dim3(V / 128, R / 128), dim3(256), 0, stream,
                     HALLB, H, WvT, H, nullptr, 0, bv, nullptr, pmax, psum);
  hipLaunchKernelGGL(k_loss, dim3(R / 4), dim3(256), 0, stream,
                     pmax, psum, HALLB, WvT, bv, cap, blk);
  hipLaunchKernelGGL(k_final, dim3(1), dim3(256), 0, stream, blk, (float*)d_out);
}